// Round 10
// baseline (1865.999 us; speedup 1.0000x reference)
//
#include <hip/hip_runtime.h>
#include <hip/hip_bf16.h>
#include <math.h>

#define B 8
#define N 4096
#define D 256
#define H 8
#define DH 32
#define M 256
#define DEPTH 4
#define HID 1024
#define NRM 0.4204482076268573f   // 32^-0.25

typedef __attribute__((ext_vector_type(8))) short short8;
typedef __attribute__((ext_vector_type(4))) float f32x4;

static __device__ __forceinline__ unsigned short f2bf(float f) {
    __hip_bfloat16 h = __float2bfloat16(f);
    return __builtin_bit_cast(unsigned short, h);
}
static __device__ __forceinline__ float bfu2f(unsigned short u) {
    unsigned int x = ((unsigned int)u) << 16;
    return __builtin_bit_cast(float, x);
}

// ---------------- h = x + pos ----------------
__global__ void add_pos_kernel(const float* __restrict__ x, const float* __restrict__ pos,
                               float* __restrict__ h) {
    int i = blockIdx.x * 256 + threadIdx.x;
    int nd = i % (N * D);
    h[i] = x[i] + pos[nd];
}

// ---------------- proj fp32 -> bf16 copy ----------------
__global__ void projbf_kernel(const float* __restrict__ in, unsigned short* __restrict__ out) {
    int i = blockIdx.x * 256 + threadIdx.x;     // DEPTH*M*DH elements
    out[i] = f2bf(in[i]);
}

// ---- weight fp32 (K x N) -> bf16 transposed (N x K), cols < slim scaled by NRM ----
__global__ __launch_bounds__(256) void wtrans_kernel(const float* __restrict__ in,
                                                     unsigned short* __restrict__ out,
                                                     int Kd, int Nd, int slim) {
    __shared__ float tl[32][33];
    int n0 = blockIdx.x * 32, k0 = blockIdx.y * 32;
    int t = threadIdx.x;
    int kk = t >> 3, c4 = (t & 7) * 4;
    float4 v = *reinterpret_cast<const float4*>(&in[(size_t)(k0 + kk) * Nd + n0 + c4]);
    tl[kk][c4 + 0] = v.x; tl[kk][c4 + 1] = v.y; tl[kk][c4 + 2] = v.z; tl[kk][c4 + 3] = v.w;
    __syncthreads();
    int nn = t >> 3, k4 = (t & 7) * 4;
    float sc = (n0 + nn < slim) ? NRM : 1.0f;
    ushort4 o;
    o.x = f2bf(tl[k4 + 0][nn] * sc); o.y = f2bf(tl[k4 + 1][nn] * sc);
    o.z = f2bf(tl[k4 + 2][nn] * sc); o.w = f2bf(tl[k4 + 3][nn] * sc);
    *reinterpret_cast<ushort4*>(&out[(size_t)(n0 + nn) * Kd + k0 + k4]) = o;
}

// ---------------- LayerNorm -> bf16 ----------------
__global__ __launch_bounds__(256) void ln_kernel(const float* __restrict__ in,
                                                 const float* __restrict__ g,
                                                 const float* __restrict__ bb,
                                                 unsigned short* __restrict__ out) {
    int wave = threadIdx.x >> 6, lane = threadIdx.x & 63;
    long row = (long)blockIdx.x * 4 + wave;
    float4 v = reinterpret_cast<const float4*>(in + row * D)[lane];
    float s = v.x + v.y + v.z + v.w;
#pragma unroll
    for (int o = 32; o >= 1; o >>= 1) s += __shfl_xor(s, o);
    float mu = s * (1.0f / D);
    float d0 = v.x - mu, d1 = v.y - mu, d2 = v.z - mu, d3 = v.w - mu;
    float ss = d0 * d0 + d1 * d1 + d2 * d2 + d3 * d3;
#pragma unroll
    for (int o = 32; o >= 1; o >>= 1) ss += __shfl_xor(ss, o);
    float inv = rsqrtf(ss * (1.0f / D) + 1e-6f);
    float4 gv = reinterpret_cast<const float4*>(g)[lane];
    float4 bv = reinterpret_cast<const float4*>(bb)[lane];
    ushort4 o4;
    o4.x = f2bf(d0 * inv * gv.x + bv.x);
    o4.y = f2bf(d1 * inv * gv.y + bv.y);
    o4.z = f2bf(d2 * inv * gv.z + bv.z);
    o4.w = f2bf(d3 * inv * gv.w + bv.w);
    *reinterpret_cast<ushort4*>(&out[row * D + lane * 4]) = o4;
}

// ---------------- bf16 MFMA GEMM: out = A(MxK) @ Bt(NxK)^T ----------------
template <bool BIAS, bool GELU_ACT, bool RESID, bool OUT16>
__global__ __launch_bounds__(256) void mgemm_kernel(const unsigned short* __restrict__ A,
                                                    const unsigned short* __restrict__ Bt,
                                                    const float* __restrict__ bias,
                                                    float* __restrict__ C,
                                                    unsigned short* __restrict__ O16,
                                                    int K, int Nc) {
    __shared__ short Als[128][40];
    __shared__ short Bls[128][40];
    int t = threadIdx.x;
    int l = t & 63, w = t >> 6;
    int wr = w >> 1, wc = w & 1;
    int nwg = gridDim.x * gridDim.y;
    int bid = blockIdx.y * gridDim.x + blockIdx.x;
    int lgid = (bid & 7) * (nwg >> 3) + (bid >> 3);
    int bx = lgid % gridDim.x;
    int by = lgid / gridDim.x;
    long m0 = (long)by * 128;
    int n0 = bx * 128;
    int lr = l & 15;
    int lg = l >> 4;
    int kp8 = lg * 8;
    int srow = t >> 2, skoff = (t & 3) * 8;

    const unsigned short* Ap0 = &A[(size_t)(m0 + srow) * K + skoff];
    const unsigned short* Ap1 = Ap0 + (size_t)64 * K;
    const unsigned short* Bp0 = &Bt[(size_t)(n0 + srow) * K + skoff];
    const unsigned short* Bp1 = Bp0 + (size_t)64 * K;

    short8 ra0 = *reinterpret_cast<const short8*>(Ap0);
    short8 ra1 = *reinterpret_cast<const short8*>(Ap1);
    short8 rb0 = *reinterpret_cast<const short8*>(Bp0);
    short8 rb1 = *reinterpret_cast<const short8*>(Bp1);

    f32x4 acc[4][4];
#pragma unroll
    for (int i = 0; i < 4; i++)
#pragma unroll
        for (int j = 0; j < 4; j++) acc[i][j] = (f32x4){0.f, 0.f, 0.f, 0.f};

    for (int k0 = 0; k0 < K; k0 += 32) {
        *reinterpret_cast<short8*>(&Als[srow][skoff]) = ra0;
        *reinterpret_cast<short8*>(&Als[srow + 64][skoff]) = ra1;
        *reinterpret_cast<short8*>(&Bls[srow][skoff]) = rb0;
        *reinterpret_cast<short8*>(&Bls[srow + 64][skoff]) = rb1;
        __syncthreads();
        if (k0 + 32 < K) {
            ra0 = *reinterpret_cast<const short8*>(Ap0 + k0 + 32);
            ra1 = *reinterpret_cast<const short8*>(Ap1 + k0 + 32);
            rb0 = *reinterpret_cast<const short8*>(Bp0 + k0 + 32);
            rb1 = *reinterpret_cast<const short8*>(Bp1 + k0 + 32);
        }
        short8 a[4], b[4];
#pragma unroll
        for (int i = 0; i < 4; i++)
            a[i] = *reinterpret_cast<const short8*>(&Als[wr * 64 + i * 16 + lr][kp8]);
#pragma unroll
        for (int j = 0; j < 4; j++)
            b[j] = *reinterpret_cast<const short8*>(&Bls[wc * 64 + j * 16 + lr][kp8]);
#pragma unroll
        for (int i = 0; i < 4; i++)
#pragma unroll
            for (int j = 0; j < 4; j++)
                acc[i][j] = __builtin_amdgcn_mfma_f32_16x16x32_bf16(b[j], a[i], acc[i][j], 0, 0, 0);
        __syncthreads();
    }

    float4 bias4[4];
    if (BIAS) {
#pragma unroll
        for (int j = 0; j < 4; j++)
            bias4[j] = *reinterpret_cast<const float4*>(&bias[n0 + wc * 64 + j * 16 + lg * 4]);
    }
#pragma unroll
    for (int i = 0; i < 4; i++) {
        long grow = m0 + wr * 64 + i * 16 + lr;
#pragma unroll
        for (int j = 0; j < 4; j++) {
            int gcol = n0 + wc * 64 + j * 16 + lg * 4;
            f32x4 v = acc[i][j];
            if (BIAS) {
                v[0] += bias4[j].x; v[1] += bias4[j].y; v[2] += bias4[j].z; v[3] += bias4[j].w;
            }
            if (GELU_ACT) {
#pragma unroll
                for (int r = 0; r < 4; r++)
                    v[r] = 0.5f * v[r] * (1.0f + erff(v[r] * 0.70710678118654752f));
            }
            if (OUT16) {
                short4 o;
                o.x = (short)f2bf(v[0]); o.y = (short)f2bf(v[1]);
                o.z = (short)f2bf(v[2]); o.w = (short)f2bf(v[3]);
                *reinterpret_cast<short4*>(&O16[grow * Nc + gcol]) = o;
            } else if (RESID) {
                float4 c0 = *reinterpret_cast<const float4*>(&C[grow * Nc + gcol]);
                c0.x += v[0]; c0.y += v[1]; c0.z += v[2]; c0.w += v[3];
                *reinterpret_cast<float4*>(&C[grow * Nc + gcol]) = c0;
            } else {
                float4 c0 = {v[0], v[1], v[2], v[3]};
                *reinterpret_cast<float4*>(&C[grow * Nc + gcol]) = c0;
            }
        }
    }
}

// ---------------- fused MLP v2: barrier-free, wave-private t1 ----------------
// wave w owns rows w*16+lr of the 64-row tile; t1 rows are wave-private in LDS.
__global__ __launch_bounds__(256) void mlp_fused_kernel(const unsigned short* __restrict__ ln16,
                                                        const unsigned short* __restrict__ w1T,
                                                        const unsigned short* __restrict__ w2T,
                                                        const float* __restrict__ b1,
                                                        const float* __restrict__ b2,
                                                        float* __restrict__ hres) {
    __shared__ __align__(16) unsigned short t1_s[64][128];   // 16 KB, XOR-swz, wave-private rows
    int t = threadIdx.x;
    int l = t & 63, w = t >> 6;
    int lr = l & 15, lg = l >> 4;
    long m0 = (long)blockIdx.x * 64;
    int row = w * 16 + lr;
    int rsw = (lr & 7) << 3;

    // ---- own A row (256 K) in registers ----
    const unsigned short* arow = ln16 + (size_t)(m0 + row) * 256;
    short8 af[8];
#pragma unroll
    for (int ks = 0; ks < 8; ks++)
        af[ks] = *reinterpret_cast<const short8*>(arow + ks * 32 + lg * 8);

    f32x4 oacc[16];
#pragma unroll
    for (int nf = 0; nf < 16; nf++) oacc[nf] = (f32x4){0.f, 0.f, 0.f, 0.f};

    for (int ch = 0; ch < HID / 128; ch++) {
        // ---- inner: t1[row][ch*128 + f*16 + lg*4 + r] ----
        f32x4 acc1[8];
#pragma unroll
        for (int f = 0; f < 8; f++) acc1[f] = (f32x4){0.f, 0.f, 0.f, 0.f};
#pragma unroll
        for (int f = 0; f < 8; f++) {
            const unsigned short* w1r = w1T + (size_t)(ch * 128 + f * 16 + lr) * 256 + lg * 8;
#pragma unroll
            for (int ks = 0; ks < 8; ks++) {
                short8 wf = *reinterpret_cast<const short8*>(w1r + ks * 32);
                acc1[f] = __builtin_amdgcn_mfma_f32_16x16x32_bf16(wf, af[ks], acc1[f], 0, 0, 0);
            }
        }
        // ---- bias1 + exact gelu -> t1 (wave-private, no barrier) ----
#pragma unroll
        for (int f = 0; f < 8; f++) {
            float4 b1v = *reinterpret_cast<const float4*>(&b1[ch * 128 + f * 16 + lg * 4]);
            f32x4 v = acc1[f];
            v[0] += b1v.x; v[1] += b1v.y; v[2] += b1v.z; v[3] += b1v.w;
#pragma unroll
            for (int r = 0; r < 4; r++)
                v[r] = 0.5f * v[r] * (1.0f + erff(v[r] * 0.70710678118654752f));
            short4 o;
            o.x = (short)f2bf(v[0]); o.y = (short)f2bf(v[1]);
            o.z = (short)f2bf(v[2]); o.w = (short)f2bf(v[3]);
            *reinterpret_cast<short4*>(&t1_s[row][(f * 16 + lg * 4) ^ rsw]) = o;
        }
        // ---- outer: oacc[nf] += W2chunk x t1 (own rows only) ----
#pragma unroll
        for (int k0 = 0; k0 < 4; k0++) {
            short8 tf = *reinterpret_cast<const short8*>(&t1_s[row][(k0 * 32 + lg * 8) ^ rsw]);
#pragma unroll
            for (int nf = 0; nf < 16; nf++) {
                short8 wf = *reinterpret_cast<const short8*>(
                    &w2T[(size_t)(nf * 16 + lr) * 1024 + ch * 128 + k0 * 32 + lg * 8]);
                oacc[nf] = __builtin_amdgcn_mfma_f32_16x16x32_bf16(wf, tf, oacc[nf], 0, 0, 0);
            }
        }
    }

    // ---- epilogue: bias2 + residual ----
    float* hrow = &hres[(size_t)(m0 + row) * 256];
#pragma unroll
    for (int nf = 0; nf < 16; nf++) {
        float4 b2v = *reinterpret_cast<const float4*>(&b2[nf * 16 + lg * 4]);
        float4 c0 = *reinterpret_cast<const float4*>(hrow + nf * 16 + lg * 4);
        c0.x += oacc[nf][0] + b2v.x; c0.y += oacc[nf][1] + b2v.y;
        c0.z += oacc[nf][2] + b2v.z; c0.w += oacc[nf][3] + b2v.w;
        *reinterpret_cast<float4*>(hrow + nf * 16 + lg * 4) = c0;
    }
}

// ---------------- kv: MFMA u + online-max + MFMA kp^T @ v, partials ----------------
#define KV_P 16
#define KV_ROWS (N / KV_P)      // 256
#define PSZ 8484                // 8192 acc + 256 asum + 32 vsum + 1 Lm + pad
__global__ __launch_bounds__(256) void kv_kernel(const unsigned short* __restrict__ qkv16,
                                                 const unsigned short* __restrict__ projbf,
                                                 float* __restrict__ kvp) {
    __shared__ __align__(16) unsigned short kp_s[256][64];    // 32 KB, XOR-swz
    __shared__ __align__(16) unsigned short vT_s[32][66];
    __shared__ float red[4];
    __shared__ float asumred[4][256];
    __shared__ float vred[256][4];
    int t = threadIdx.x;
    int l = t & 63, w = t >> 6;
    int lr = l & 15, lg = l >> 4;
    int bh = blockIdx.x, b = bh >> 3, h = bh & 7;
    int n0 = blockIdx.y * KV_ROWS;
    int rsw = (lr & 7) << 3;

    f32x4 kvacc[4][2];
#pragma unroll
    for (int mf = 0; mf < 4; mf++)
#pragma unroll
        for (int dd = 0; dd < 2; dd++) kvacc[mf][dd] = (f32x4){0.f, 0.f, 0.f, 0.f};
    float asum_p[16];
#pragma unroll
    for (int f = 0; f < 16; f++) asum_p[f] = 0.f;
    float4 vs4 = {0.f, 0.f, 0.f, 0.f};
    float Lm = -1e30f;

    for (int c = 0; c < KV_ROWS / 64; c++) {
        size_t kbase = ((size_t)(b * N) + n0 + c * 64 + w * 16 + lr) * 768 + 256 + h * 32 + lg * 8;
        short8 aq = *reinterpret_cast<const short8*>(qkv16 + kbase);
        float sq = 0.f;
#pragma unroll
        for (int e = 0; e < 8; e++) {
            float xx = bfu2f((unsigned short)aq[e]);
            sq += xx * xx;
        }
        sq += __shfl_xor(sq, 16);
        sq += __shfl_xor(sq, 32);
        f32x4 ua[16];
#pragma unroll
        for (int f = 0; f < 16; f++) {
            short8 bq = *reinterpret_cast<const short8*>(projbf + (f * 16 + lr) * 32 + lg * 8);
            ua[f] = __builtin_amdgcn_mfma_f32_16x16x32_bf16(aq, bq, (f32x4){0.f, 0.f, 0.f, 0.f}, 0, 0, 0);
        }
        float cm = -1e30f;
#pragma unroll
        for (int f = 0; f < 16; f++)
#pragma unroll
            for (int r = 0; r < 4; r++) cm = fmaxf(cm, ua[f][r]);
#pragma unroll
        for (int o = 1; o < 64; o <<= 1) cm = fmaxf(cm, __shfl_xor(cm, o));
        if (l == 0) red[w] = cm;
        __syncthreads();
        float bm = fmaxf(fmaxf(red[0], red[1]), fmaxf(red[2], red[3]));
        if (bm > Lm) {
            float sc = __expf(Lm - bm);
#pragma unroll
            for (int mf = 0; mf < 4; mf++)
#pragma unroll
                for (int dd = 0; dd < 2; dd++) {
                    kvacc[mf][dd][0] *= sc; kvacc[mf][dd][1] *= sc;
                    kvacc[mf][dd][2] *= sc; kvacc[mf][dd][3] *= sc;
                }
#pragma unroll
            for (int f = 0; f < 16; f++) asum_p[f] *= sc;
            Lm = bm;
        }
        float dgr[4];
#pragma unroll
        for (int r = 0; r < 4; r++) dgr[r] = 0.5f * __shfl(sq, lg * 4 + r);
        int cbase = (w * 16 + lg * 4) ^ rsw;
#pragma unroll
        for (int f = 0; f < 16; f++) {
            float p0 = __expf(ua[f][0] - dgr[0] - Lm);
            float p1 = __expf(ua[f][1] - dgr[1] - Lm);
            float p2 = __expf(ua[f][2] - dgr[2] - Lm);
            float p3 = __expf(ua[f][3] - dgr[3] - Lm);
            asum_p[f] += p0 + p1 + p2 + p3;
            short4 o;
            o.x = (short)f2bf(p0); o.y = (short)f2bf(p1);
            o.z = (short)f2bf(p2); o.w = (short)f2bf(p3);
            *reinterpret_cast<short4*>(&kp_s[f * 16 + lr][cbase]) = o;
        }
#pragma unroll
        for (int ii = 0; ii < 2; ii++) {
            int idx = t + ii * 256;
            int nn = idx >> 3, dz = (idx & 7) * 4;
            const unsigned short* vp =
                qkv16 + ((size_t)(b * N) + n0 + c * 64 + nn) * 768 + 512 + h * 32 + dz;
            short4 vv = *reinterpret_cast<const short4*>(vp);
            float v0 = bfu2f((unsigned short)vv.x), v1 = bfu2f((unsigned short)vv.y);
            float v2 = bfu2f((unsigned short)vv.z), v3 = bfu2f((unsigned short)vv.w);
            vs4.x += v0; vs4.y += v1; vs4.z += v2; vs4.w += v3;
            vT_s[dz + 0][nn] = (unsigned short)vv.x; vT_s[dz + 1][nn] = (unsigned short)vv.y;
            vT_s[dz + 2][nn] = (unsigned short)vv.z; vT_s[dz + 3][nn] = (unsigned short)vv.w;
        }
        __syncthreads();
#pragma unroll
        for (int ks = 0; ks < 2; ks++) {
            short8 bv0 = *reinterpret_cast<const short8*>(&vT_s[lr][ks * 32 + lg * 8]);
            short8 bv1 = *reinterpret_cast<const short8*>(&vT_s[16 + lr][ks * 32 + lg * 8]);
#pragma unroll
            for (int mf = 0; mf < 4; mf++) {
                short8 am = *reinterpret_cast<const short8*>(
                    &kp_s[w * 64 + mf * 16 + lr][(ks * 32 + lg * 8) ^ rsw]);
                kvacc[mf][0] = __builtin_amdgcn_mfma_f32_16x16x32_bf16(am, bv0, kvacc[mf][0], 0, 0, 0);
                kvacc[mf][1] = __builtin_amdgcn_mfma_f32_16x16x32_bf16(am, bv1, kvacc[mf][1], 0, 0, 0);
            }
        }
    }
#pragma unroll
    for (int f = 0; f < 16; f++) {
        asum_p[f] += __shfl_xor(asum_p[f], 16);
        asum_p[f] += __shfl_xor(asum_p[f], 32);
    }
    if (l < 16) {
#pragma unroll
        for (int f = 0; f < 16; f++) asumred[w][f * 16 + l] = asum_p[f];
    }
    vred[t][0] = vs4.x; vred[t][1] = vs4.y; vred[t][2] = vs4.z; vred[t][3] = vs4.w;
    __syncthreads();
    size_t base = ((size_t)bh * KV_P + blockIdx.y) * PSZ;
#pragma unroll
    for (int mf = 0; mf < 4; mf++)
#pragma unroll
        for (int dd = 0; dd < 2; dd++)
#pragma unroll
            for (int r = 0; r < 4; r++) {
                int m = w * 64 + mf * 16 + lg * 4 + r;
                int d = dd * 16 + lr;
                kvp[base + m * 32 + d] = kvacc[mf][dd][r];
            }
    {
        float s = asumred[0][t] + asumred[1][t] + asumred[2][t] + asumred[3][t];
        kvp[base + 8192 + t] = s;
    }
    if (t < 32) {
        int f4g = t >> 2, cc = t & 3;
        float s = 0.f;
#pragma unroll
        for (int g = 0; g < 32; g++) s += vred[g * 8 + f4g][cc];
        kvp[base + 8448 + t] = s;
    }
    if (t == 0) kvp[base + 8480] = Lm;
}

// ---------------- combine partials -> kvT bf16, ksum (grid B*H*4) ----------------
__global__ __launch_bounds__(256) void kv_combine_kernel(const float* __restrict__ kvp,
                                                         unsigned short* __restrict__ kvTb,
                                                         float* __restrict__ ksumf) {
    __shared__ float vst[32];
    int t = threadIdx.x;
    int bh = blockIdx.x >> 2, mq = blockIdx.x & 3;
    size_t base0 = (size_t)bh * KV_P * PSZ;
    float Lp[KV_P];
    float gm = -1e30f;
#pragma unroll
    for (int p = 0; p < KV_P; p++) {
        Lp[p] = kvp[base0 + p * PSZ + 8480];
        gm = fmaxf(gm, Lp[p]);
    }
    if (t < 32) {
        float s = 0.f;
#pragma unroll
        for (int p = 0; p < KV_P; p++) s += kvp[base0 + p * PSZ + 8448 + t];
        vst[t] = s;
    }
    __syncthreads();
    int m = mq * 64 + (t >> 2);
    int d0 = (t & 3) * 8;
    float4 av0 = {0.f, 0.f, 0.f, 0.f}, av1 = {0.f, 0.f, 0.f, 0.f};
    float S = 0.f;
#pragma unroll
    for (int p = 0; p < KV_P; p++) {
        float e = __expf(Lp[p] - gm);
        size_t pb = base0 + p * PSZ;
        float4 a = *reinterpret_cast<const float4*>(&kvp[pb + m * 32 + d0]);
        float4 bq = *reinterpret_cast<const float4*>(&kvp[pb + m * 32 + d0 + 4]);
        av0.x += e * a.x; av0.y += e * a.y; av0.z += e * a.z; av0.w += e * a.w;
        av1.x += e * bq.x; av1.y += e * bq.y; av1.z += e * bq.z; av1.w += e * bq.w;
        if ((t & 3) == 0) S += e * kvp[pb + 8192 + m];
    }
    float o[8];
    o[0] = av0.x; o[1] = av0.y; o[2] = av0.z; o[3] = av0.w;
    o[4] = av1.x; o[5] = av1.y; o[6] = av1.z; o[7] = av1.w;
#pragma unroll
    for (int j = 0; j < 8; j++) {
        float v = (o[j] + 1e-4f * vst[d0 + j]) * 0.0625f;
        kvTb[((size_t)bh * 32 + d0 + j) * 256 + m] = f2bf(v);
    }
    if ((t & 3) == 0) ksumf[bh * 256 + m] = (S + 1e-4f * (float)N) * 0.0625f;
}

// ---------------- q-side fused attention ----------------
#define ATT_TILES 8
__global__ __launch_bounds__(256) void attn_kernel(const unsigned short* __restrict__ qkv16,
                                                   const unsigned short* __restrict__ projbf,
                                                   const unsigned short* __restrict__ kvTb,
                                                   const float* __restrict__ ksumf,
                                                   unsigned short* __restrict__ attn16) {
    __shared__ __align__(16) unsigned short qp_s[64 * 256];   // 32 KB, swizzled
    int t = threadIdx.x;
    int l = t & 63, w = t >> 6;
    int lr = l & 15, lg = l >> 4;
    int bh = blockIdx.x, b = bh >> 3, h = bh & 7;
    int swz = (lr & 7) << 3;
    int row = w * 16 + lr;

    const unsigned short* kvb = kvTb + (size_t)bh * 32 * 256;
    short8 kva0[8], kva1[8];
#pragma unroll
    for (int k0 = 0; k0 < 8; k0++) {
        kva0[k0] = *reinterpret_cast<const short8*>(kvb + (size_t)lr * 256 + k0 * 32 + lg * 8);
        kva1[k0] = *reinterpret_cast<const short8*>(kvb + (size_t)(16 + lr) * 256 + k0 * 32 + lg * 8);
    }

    int tile0 = blockIdx.y * ATT_TILES;
    size_t qstep = (size_t)64 * 768;
    size_t qbase = ((size_t)(b * N) + tile0 * 64 + w * 16 + lr) * 768 + h * 32 + lg * 8;
    short8 qf = *reinterpret_cast<const short8*>(qkv16 + qbase);

    for (int tl = 0; tl < ATT_TILES; tl++) {
        short8 qfn = qf;
        if (tl < ATT_TILES - 1)
            qfn = *reinterpret_cast<const short8*>(qkv16 + qbase + (size_t)(tl + 1) * qstep);

        float sq = 0.f;
#pragma unroll
        for (int e = 0; e < 8; e++) {
            float xx = bfu2f((unsigned short)qf[e]);
            sq += xx * xx;
        }
        sq += __shfl_xor(sq, 16);
        sq += __shfl_xor(sq, 32);
        float dg = 0.5f * sq;

        f32x4 ua[16];
#pragma unroll
        for (int f = 0; f < 16; f++) {
            short8 bq = *reinterpret_cast<const short8*>(projbf + (f * 16 + lr) * 32 + lg * 8);
            ua[f] = __builtin_amdgcn_mfma_f32_16x16x32_bf16(bq, qf, (f32x4){0.f, 0.f, 0.f, 0.f}, 0, 0, 0);
        }

        float mx = -1e30f;
#pragma unroll
        for (int f = 0; f < 16; f++)
#pragma unroll
            for (int r = 0; r < 4; r++) mx = fmaxf(mx, ua[f][r]);
        mx = fmaxf(mx, __shfl_xor(mx, 16));
        mx = fmaxf(mx, __shfl_xor(mx, 32));

        float zs = 0.f;
#pragma unroll
        for (int f = 0; f < 16; f++) {
            float4 ks4 = *reinterpret_cast<const float4*>(&ksumf[bh * 256 + f * 16 + lg * 4]);
            float p0 = (__expf(ua[f][0] - dg - mx) + 1e-4f) * 0.0625f;
            float p1 = (__expf(ua[f][1] - dg - mx) + 1e-4f) * 0.0625f;
            float p2 = (__expf(ua[f][2] - dg - mx) + 1e-4f) * 0.0625f;
            float p3 = (__expf(ua[f][3] - dg - mx) + 1e-4f) * 0.0625f;
            zs += p0 * ks4.x + p1 * ks4.y + p2 * ks4.z + p3 * ks4.w;
            short4 o;
            o.x = (short)f2bf(p0); o.y = (short)f2bf(p1);
            o.z = (short)f2bf(p2); o.w = (short)f2bf(p3);
            *reinterpret_cast<short4*>(&qp_s[row * 256 + ((f * 16 + lg * 4) ^ swz)]) = o;
        }
        zs += __shfl_xor(zs, 16);
        zs += __shfl_xor(zs, 32);
        float zf = 1.0f / (zs + 1e-6f);

        f32x4 oacc[2];
        oacc[0] = (f32x4){0.f, 0.f, 0.f, 0.f};
        oacc[1] = (f32x4){0.f, 0.f, 0.f, 0.f};
#pragma unroll
        for (int k0 = 0; k0 < 8; k0++) {
            short8 qpf = *reinterpret_cast<const short8*>(
                &qp_s[row * 256 + ((k0 * 32 + lg * 8) ^ swz)]);
            oacc[0] = __builtin_amdgcn_mfma_f32_16x16x32_bf16(kva0[k0], qpf, oacc[0], 0, 0, 0);
            oacc[1] = __builtin_amdgcn_mfma_f32_16x16x32_bf16(kva1[k0], qpf, oacc[1], 0, 0, 0);
        }
        size_t orow = ((size_t)(b * N) + (tile0 + tl) * 64 + w * 16 + lr) * 256 + h * 32;
#pragma unroll
        for (int dd = 0; dd < 2; dd++) {
            short4 o;
            o.x = (short)f2bf(oacc[dd][0] * zf);
            o.y = (short)f2bf(oacc[dd][1] * zf);
            o.z = (short)f2bf(oacc[dd][2] * zf);
            o.w = (short)f2bf(oacc[dd][3] * zf);
            *reinterpret_cast<short4*>(&attn16[orow + dd * 16 + lg * 4]) = o;
        }
        qf = qfn;
    }
}

extern "C" void kernel_launch(void* const* d_in, const int* in_sizes, int n_in,
                              void* d_out, int out_size, void* d_ws, size_t ws_size,
                              hipStream_t stream) {
    const float* x = (const float*)d_in[0];
    const float* pos = (const float*)d_in[1];
    const float* g1 = (const float*)d_in[2];
    const float* b1 = (const float*)d_in[3];
    const float* g2 = (const float*)d_in[4];
    const float* b2 = (const float*)d_in[5];
    const float* Wqkv = (const float*)d_in[6];
    const float* Wproj = (const float*)d_in[7];
    const float* bproj = (const float*)d_in[8];
    const float* W1 = (const float*)d_in[9];
    const float* b1m = (const float*)d_in[10];
    const float* W2 = (const float*)d_in[11];
    const float* b2m = (const float*)d_in[12];
    const float* projm = (const float*)d_in[13];

    float* h = (float*)d_out;
    char* p = (char*)d_ws;
    auto alloc = [&](size_t bytes) { char* r = p; p += (bytes + 255) & ~(size_t)255; return r; };
    unsigned short* wbf    = (unsigned short*)alloc((size_t)DEPTH * 786432 * 2);
    unsigned short* projb  = (unsigned short*)alloc((size_t)DEPTH * M * DH * 2);
    unsigned short* ln16   = (unsigned short*)alloc((size_t)B * N * D * 2);
    unsigned short* qkv16  = (unsigned short*)alloc((size_t)B * N * 3 * D * 2);
    unsigned short* attn16 = (unsigned short*)alloc((size_t)B * N * D * 2);
    float* kvp             = (float*)alloc((size_t)64 * KV_P * PSZ * 4);
    unsigned short* kvTb   = (unsigned short*)alloc((size_t)64 * 32 * 256 * 2);
    float* ksumf           = (float*)alloc((size_t)64 * 256 * 4);

    for (int l = 0; l < DEPTH; l++) {
        size_t lb = (size_t)l * 786432;
        wtrans_kernel<<<dim3(768 / 32, 256 / 32), 256, 0, stream>>>(
            Wqkv + (size_t)l * D * 3 * D, wbf + lb + 0, 256, 768, 512);
        wtrans_kernel<<<dim3(256 / 32, 256 / 32), 256, 0, stream>>>(
            Wproj + (size_t)l * D * D, wbf + lb + 196608, 256, 256, 0);
        wtrans_kernel<<<dim3(1024 / 32, 256 / 32), 256, 0, stream>>>(
            W1 + (size_t)l * D * HID, wbf + lb + 262144, 256, 1024, 0);
        wtrans_kernel<<<dim3(256 / 32, 1024 / 32), 256, 0, stream>>>(
            W2 + (size_t)l * HID * D, wbf + lb + 524288, 1024, 256, 0);
    }
    projbf_kernel<<<DEPTH * M * DH / 256, 256, 0, stream>>>(projm, projb);

    add_pos_kernel<<<B * N * D / 256, 256, 0, stream>>>(x, pos, h);

    for (int l = 0; l < DEPTH; l++) {
        size_t lb = (size_t)l * 786432;
        const unsigned short* wqT = wbf + lb + 0;
        const unsigned short* wpT = wbf + lb + 196608;
        const unsigned short* w1T = wbf + lb + 262144;
        const unsigned short* w2T = wbf + lb + 524288;
        const float* bp = bproj + (size_t)l * D;
        const float* b1l = b1m + (size_t)l * HID;
        const float* b2l = b2m + (size_t)l * D;
        const unsigned short* prb = projb + (size_t)l * M * DH;

        ln_kernel<<<B * N / 4, 256, 0, stream>>>(h, g1, b1, ln16);
        mgemm_kernel<false, false, false, true><<<dim3(768 / 128, B * N / 128), 256, 0, stream>>>(
            ln16, wqT, nullptr, nullptr, qkv16, 256, 768);
        kv_kernel<<<dim3(B * H, KV_P), 256, 0, stream>>>(qkv16, prb, kvp);
        kv_combine_kernel<<<B * H * 4, 256, 0, stream>>>(kvp, kvTb, ksumf);
        attn_kernel<<<dim3(B * H, (N / 64) / ATT_TILES), 256, 0, stream>>>(
            qkv16, prb, kvTb, ksumf, attn16);
        mgemm_kernel<true, false, true, false><<<dim3(256 / 128, B * N / 128), 256, 0, stream>>>(
            attn16, wpT, bp, h, nullptr, 256, 256);
        ln_kernel<<<B * N / 4, 256, 0, stream>>>(h, g2, b2, ln16);
        mlp_fused_kernel<<<B * N / 64, 256, 0, stream>>>(ln16, w1T, w2T, b1l, b2l, h);
    }
}

// Round 11
// 975.078 us; speedup vs baseline: 1.9137x; 1.9137x over previous
//
#include <hip/hip_runtime.h>
#include <hip/hip_bf16.h>
#include <math.h>

#define B 8
#define N 4096
#define D 256
#define H 8
#define DH 32
#define M 256
#define DEPTH 4
#define HID 1024
#define NRM 0.4204482076268573f   // 32^-0.25

typedef __attribute__((ext_vector_type(8))) short short8;
typedef __attribute__((ext_vector_type(4))) float f32x4;

static __device__ __forceinline__ unsigned short f2bf(float f) {
    __hip_bfloat16 h = __float2bfloat16(f);
    return __builtin_bit_cast(unsigned short, h);
}
static __device__ __forceinline__ float bfu2f(unsigned short u) {
    unsigned int x = ((unsigned int)u) << 16;
    return __builtin_bit_cast(float, x);
}

// ---------------- h = x + pos ----------------
__global__ void add_pos_kernel(const float* __restrict__ x, const float* __restrict__ pos,
                               float* __restrict__ h) {
    int i = blockIdx.x * 256 + threadIdx.x;
    int nd = i % (N * D);
    h[i] = x[i] + pos[nd];
}

// ---------------- proj fp32 -> bf16 copy ----------------
__global__ void projbf_kernel(const float* __restrict__ in, unsigned short* __restrict__ out) {
    int i = blockIdx.x * 256 + threadIdx.x;     // DEPTH*M*DH elements
    out[i] = f2bf(in[i]);
}

// ---- weight fp32 (K x N) -> bf16 transposed (N x K), cols < slim scaled by NRM ----
__global__ __launch_bounds__(256) void wtrans_kernel(const float* __restrict__ in,
                                                     unsigned short* __restrict__ out,
                                                     int Kd, int Nd, int slim) {
    __shared__ float tl[32][33];
    int n0 = blockIdx.x * 32, k0 = blockIdx.y * 32;
    int t = threadIdx.x;
    int kk = t >> 3, c4 = (t & 7) * 4;
    float4 v = *reinterpret_cast<const float4*>(&in[(size_t)(k0 + kk) * Nd + n0 + c4]);
    tl[kk][c4 + 0] = v.x; tl[kk][c4 + 1] = v.y; tl[kk][c4 + 2] = v.z; tl[kk][c4 + 3] = v.w;
    __syncthreads();
    int nn = t >> 3, k4 = (t & 7) * 4;
    float sc = (n0 + nn < slim) ? NRM : 1.0f;
    ushort4 o;
    o.x = f2bf(tl[k4 + 0][nn] * sc); o.y = f2bf(tl[k4 + 1][nn] * sc);
    o.z = f2bf(tl[k4 + 2][nn] * sc); o.w = f2bf(tl[k4 + 3][nn] * sc);
    *reinterpret_cast<ushort4*>(&out[(size_t)(n0 + nn) * Kd + k0 + k4]) = o;
}

// ---------------- LayerNorm -> bf16 ----------------
__global__ __launch_bounds__(256) void ln_kernel(const float* __restrict__ in,
                                                 const float* __restrict__ g,
                                                 const float* __restrict__ bb,
                                                 unsigned short* __restrict__ out) {
    int wave = threadIdx.x >> 6, lane = threadIdx.x & 63;
    long row = (long)blockIdx.x * 4 + wave;
    float4 v = reinterpret_cast<const float4*>(in + row * D)[lane];
    float s = v.x + v.y + v.z + v.w;
#pragma unroll
    for (int o = 32; o >= 1; o >>= 1) s += __shfl_xor(s, o);
    float mu = s * (1.0f / D);
    float d0 = v.x - mu, d1 = v.y - mu, d2 = v.z - mu, d3 = v.w - mu;
    float ss = d0 * d0 + d1 * d1 + d2 * d2 + d3 * d3;
#pragma unroll
    for (int o = 32; o >= 1; o >>= 1) ss += __shfl_xor(ss, o);
    float inv = rsqrtf(ss * (1.0f / D) + 1e-6f);
    float4 gv = reinterpret_cast<const float4*>(g)[lane];
    float4 bv = reinterpret_cast<const float4*>(bb)[lane];
    ushort4 o4;
    o4.x = f2bf(d0 * inv * gv.x + bv.x);
    o4.y = f2bf(d1 * inv * gv.y + bv.y);
    o4.z = f2bf(d2 * inv * gv.z + bv.z);
    o4.w = f2bf(d3 * inv * gv.w + bv.w);
    *reinterpret_cast<ushort4*>(&out[row * D + lane * 4]) = o4;
}

// ---------------- bf16 MFMA GEMM: out = A(MxK) @ Bt(NxK)^T ----------------
// XCD-swizzled grid, padded LDS (80B rows), reg-prefetch pipeline,
// operand-swapped MFMA (reg-dim = N) -> vectorized epilogue.
template <bool BIAS, bool GELU_ACT, bool RESID, bool OUT16>
__global__ __launch_bounds__(256) void mgemm_kernel(const unsigned short* __restrict__ A,
                                                    const unsigned short* __restrict__ Bt,
                                                    const float* __restrict__ bias,
                                                    float* __restrict__ C,
                                                    unsigned short* __restrict__ O16,
                                                    int K, int Nc) {
    __shared__ short Als[128][40];
    __shared__ short Bls[128][40];
    int t = threadIdx.x;
    int l = t & 63, w = t >> 6;
    int wr = w >> 1, wc = w & 1;
    int nwg = gridDim.x * gridDim.y;
    int bid = blockIdx.y * gridDim.x + blockIdx.x;
    int lgid = (bid & 7) * (nwg >> 3) + (bid >> 3);
    int bx = lgid % gridDim.x;
    int by = lgid / gridDim.x;
    long m0 = (long)by * 128;
    int n0 = bx * 128;
    int lr = l & 15;
    int lg = l >> 4;
    int kp8 = lg * 8;
    int srow = t >> 2, skoff = (t & 3) * 8;

    const unsigned short* Ap0 = &A[(size_t)(m0 + srow) * K + skoff];
    const unsigned short* Ap1 = Ap0 + (size_t)64 * K;
    const unsigned short* Bp0 = &Bt[(size_t)(n0 + srow) * K + skoff];
    const unsigned short* Bp1 = Bp0 + (size_t)64 * K;

    short8 ra0 = *reinterpret_cast<const short8*>(Ap0);
    short8 ra1 = *reinterpret_cast<const short8*>(Ap1);
    short8 rb0 = *reinterpret_cast<const short8*>(Bp0);
    short8 rb1 = *reinterpret_cast<const short8*>(Bp1);

    f32x4 acc[4][4];
#pragma unroll
    for (int i = 0; i < 4; i++)
#pragma unroll
        for (int j = 0; j < 4; j++) acc[i][j] = (f32x4){0.f, 0.f, 0.f, 0.f};

    for (int k0 = 0; k0 < K; k0 += 32) {
        *reinterpret_cast<short8*>(&Als[srow][skoff]) = ra0;
        *reinterpret_cast<short8*>(&Als[srow + 64][skoff]) = ra1;
        *reinterpret_cast<short8*>(&Bls[srow][skoff]) = rb0;
        *reinterpret_cast<short8*>(&Bls[srow + 64][skoff]) = rb1;
        __syncthreads();
        if (k0 + 32 < K) {
            ra0 = *reinterpret_cast<const short8*>(Ap0 + k0 + 32);
            ra1 = *reinterpret_cast<const short8*>(Ap1 + k0 + 32);
            rb0 = *reinterpret_cast<const short8*>(Bp0 + k0 + 32);
            rb1 = *reinterpret_cast<const short8*>(Bp1 + k0 + 32);
        }
        short8 a[4], b[4];
#pragma unroll
        for (int i = 0; i < 4; i++)
            a[i] = *reinterpret_cast<const short8*>(&Als[wr * 64 + i * 16 + lr][kp8]);
#pragma unroll
        for (int j = 0; j < 4; j++)
            b[j] = *reinterpret_cast<const short8*>(&Bls[wc * 64 + j * 16 + lr][kp8]);
#pragma unroll
        for (int i = 0; i < 4; i++)
#pragma unroll
            for (int j = 0; j < 4; j++)
                acc[i][j] = __builtin_amdgcn_mfma_f32_16x16x32_bf16(b[j], a[i], acc[i][j], 0, 0, 0);
        __syncthreads();
    }

    float4 bias4[4];
    if (BIAS) {
#pragma unroll
        for (int j = 0; j < 4; j++)
            bias4[j] = *reinterpret_cast<const float4*>(&bias[n0 + wc * 64 + j * 16 + lg * 4]);
    }
#pragma unroll
    for (int i = 0; i < 4; i++) {
        long grow = m0 + wr * 64 + i * 16 + lr;
#pragma unroll
        for (int j = 0; j < 4; j++) {
            int gcol = n0 + wc * 64 + j * 16 + lg * 4;
            f32x4 v = acc[i][j];
            if (BIAS) {
                v[0] += bias4[j].x; v[1] += bias4[j].y; v[2] += bias4[j].z; v[3] += bias4[j].w;
            }
            if (GELU_ACT) {
#pragma unroll
                for (int r = 0; r < 4; r++)
                    v[r] = 0.5f * v[r] * (1.0f + erff(v[r] * 0.70710678118654752f));
            }
            if (OUT16) {
                short4 o;
                o.x = (short)f2bf(v[0]); o.y = (short)f2bf(v[1]);
                o.z = (short)f2bf(v[2]); o.w = (short)f2bf(v[3]);
                *reinterpret_cast<short4*>(&O16[grow * Nc + gcol]) = o;
            } else if (RESID) {
                float4 c0 = *reinterpret_cast<const float4*>(&C[grow * Nc + gcol]);
                c0.x += v[0]; c0.y += v[1]; c0.z += v[2]; c0.w += v[3];
                *reinterpret_cast<float4*>(&C[grow * Nc + gcol]) = c0;
            } else {
                float4 c0 = {v[0], v[1], v[2], v[3]};
                *reinterpret_cast<float4*>(&C[grow * Nc + gcol]) = c0;
            }
        }
    }
}

// ---------------- kv: MFMA u + online-max + MFMA kp^T @ v, partials ----------------
#define KV_P 16
#define KV_ROWS (N / KV_P)      // 256
#define PSZ 8484                // 8192 acc + 256 asum + 32 vsum + 1 Lm + pad
__global__ __launch_bounds__(256) void kv_kernel(const unsigned short* __restrict__ qkv16,
                                                 const unsigned short* __restrict__ projbf,
                                                 float* __restrict__ kvp) {
    __shared__ __align__(16) unsigned short kp_s[256][64];    // 32 KB, XOR-swz
    __shared__ __align__(16) unsigned short vT_s[32][66];
    __shared__ float red[4];
    __shared__ float asumred[4][256];
    __shared__ float vred[256][4];
    int t = threadIdx.x;
    int l = t & 63, w = t >> 6;
    int lr = l & 15, lg = l >> 4;
    int bh = blockIdx.x, b = bh >> 3, h = bh & 7;
    int n0 = blockIdx.y * KV_ROWS;
    int rsw = (lr & 7) << 3;

    f32x4 kvacc[4][2];
#pragma unroll
    for (int mf = 0; mf < 4; mf++)
#pragma unroll
        for (int dd = 0; dd < 2; dd++) kvacc[mf][dd] = (f32x4){0.f, 0.f, 0.f, 0.f};
    float asum_p[16];
#pragma unroll
    for (int f = 0; f < 16; f++) asum_p[f] = 0.f;
    float4 vs4 = {0.f, 0.f, 0.f, 0.f};
    float Lm = -1e30f;

    for (int c = 0; c < KV_ROWS / 64; c++) {
        size_t kbase = ((size_t)(b * N) + n0 + c * 64 + w * 16 + lr) * 768 + 256 + h * 32 + lg * 8;
        short8 aq = *reinterpret_cast<const short8*>(qkv16 + kbase);
        float sq = 0.f;
#pragma unroll
        for (int e = 0; e < 8; e++) {
            float xx = bfu2f((unsigned short)aq[e]);
            sq += xx * xx;
        }
        sq += __shfl_xor(sq, 16);
        sq += __shfl_xor(sq, 32);
        f32x4 ua[16];
#pragma unroll
        for (int f = 0; f < 16; f++) {
            short8 bq = *reinterpret_cast<const short8*>(projbf + (f * 16 + lr) * 32 + lg * 8);
            ua[f] = __builtin_amdgcn_mfma_f32_16x16x32_bf16(aq, bq, (f32x4){0.f, 0.f, 0.f, 0.f}, 0, 0, 0);
        }
        float cm = -1e30f;
#pragma unroll
        for (int f = 0; f < 16; f++)
#pragma unroll
            for (int r = 0; r < 4; r++) cm = fmaxf(cm, ua[f][r]);
#pragma unroll
        for (int o = 1; o < 64; o <<= 1) cm = fmaxf(cm, __shfl_xor(cm, o));
        if (l == 0) red[w] = cm;
        __syncthreads();
        float bm = fmaxf(fmaxf(red[0], red[1]), fmaxf(red[2], red[3]));
        if (bm > Lm) {
            float sc = __expf(Lm - bm);
#pragma unroll
            for (int mf = 0; mf < 4; mf++)
#pragma unroll
                for (int dd = 0; dd < 2; dd++) {
                    kvacc[mf][dd][0] *= sc; kvacc[mf][dd][1] *= sc;
                    kvacc[mf][dd][2] *= sc; kvacc[mf][dd][3] *= sc;
                }
#pragma unroll
            for (int f = 0; f < 16; f++) asum_p[f] *= sc;
            Lm = bm;
        }
        float dgr[4];
#pragma unroll
        for (int r = 0; r < 4; r++) dgr[r] = 0.5f * __shfl(sq, lg * 4 + r);
        int cbase = (w * 16 + lg * 4) ^ rsw;
#pragma unroll
        for (int f = 0; f < 16; f++) {
            float p0 = __expf(ua[f][0] - dgr[0] - Lm);
            float p1 = __expf(ua[f][1] - dgr[1] - Lm);
            float p2 = __expf(ua[f][2] - dgr[2] - Lm);
            float p3 = __expf(ua[f][3] - dgr[3] - Lm);
            asum_p[f] += p0 + p1 + p2 + p3;
            short4 o;
            o.x = (short)f2bf(p0); o.y = (short)f2bf(p1);
            o.z = (short)f2bf(p2); o.w = (short)f2bf(p3);
            *reinterpret_cast<short4*>(&kp_s[f * 16 + lr][cbase]) = o;
        }
#pragma unroll
        for (int ii = 0; ii < 2; ii++) {
            int idx = t + ii * 256;
            int nn = idx >> 3, dz = (idx & 7) * 4;
            const unsigned short* vp =
                qkv16 + ((size_t)(b * N) + n0 + c * 64 + nn) * 768 + 512 + h * 32 + dz;
            short4 vv = *reinterpret_cast<const short4*>(vp);
            float v0 = bfu2f((unsigned short)vv.x), v1 = bfu2f((unsigned short)vv.y);
            float v2 = bfu2f((unsigned short)vv.z), v3 = bfu2f((unsigned short)vv.w);
            vs4.x += v0; vs4.y += v1; vs4.z += v2; vs4.w += v3;
            vT_s[dz + 0][nn] = (unsigned short)vv.x; vT_s[dz + 1][nn] = (unsigned short)vv.y;
            vT_s[dz + 2][nn] = (unsigned short)vv.z; vT_s[dz + 3][nn] = (unsigned short)vv.w;
        }
        __syncthreads();
#pragma unroll
        for (int ks = 0; ks < 2; ks++) {
            short8 bv0 = *reinterpret_cast<const short8*>(&vT_s[lr][ks * 32 + lg * 8]);
            short8 bv1 = *reinterpret_cast<const short8*>(&vT_s[16 + lr][ks * 32 + lg * 8]);
#pragma unroll
            for (int mf = 0; mf < 4; mf++) {
                short8 am = *reinterpret_cast<const short8*>(
                    &kp_s[w * 64 + mf * 16 + lr][(ks * 32 + lg * 8) ^ rsw]);
                kvacc[mf][0] = __builtin_amdgcn_mfma_f32_16x16x32_bf16(am, bv0, kvacc[mf][0], 0, 0, 0);
                kvacc[mf][1] = __builtin_amdgcn_mfma_f32_16x16x32_bf16(am, bv1, kvacc[mf][1], 0, 0, 0);
            }
        }
    }
#pragma unroll
    for (int f = 0; f < 16; f++) {
        asum_p[f] += __shfl_xor(asum_p[f], 16);
        asum_p[f] += __shfl_xor(asum_p[f], 32);
    }
    if (l < 16) {
#pragma unroll
        for (int f = 0; f < 16; f++) asumred[w][f * 16 + l] = asum_p[f];
    }
    vred[t][0] = vs4.x; vred[t][1] = vs4.y; vred[t][2] = vs4.z; vred[t][3] = vs4.w;
    __syncthreads();
    size_t base = ((size_t)bh * KV_P + blockIdx.y) * PSZ;
#pragma unroll
    for (int mf = 0; mf < 4; mf++)
#pragma unroll
        for (int dd = 0; dd < 2; dd++)
#pragma unroll
            for (int r = 0; r < 4; r++) {
                int m = w * 64 + mf * 16 + lg * 4 + r;
                int d = dd * 16 + lr;
                kvp[base + m * 32 + d] = kvacc[mf][dd][r];
            }
    {
        float s = asumred[0][t] + asumred[1][t] + asumred[2][t] + asumred[3][t];
        kvp[base + 8192 + t] = s;
    }
    if (t < 32) {
        int f4g = t >> 2, cc = t & 3;
        float s = 0.f;
#pragma unroll
        for (int g = 0; g < 32; g++) s += vred[g * 8 + f4g][cc];
        kvp[base + 8448 + t] = s;
    }
    if (t == 0) kvp[base + 8480] = Lm;
}

// ---------------- combine partials -> kvT bf16, ksum (grid B*H*4) ----------------
__global__ __launch_bounds__(256) void kv_combine_kernel(const float* __restrict__ kvp,
                                                         unsigned short* __restrict__ kvTb,
                                                         float* __restrict__ ksumf) {
    __shared__ float vst[32];
    int t = threadIdx.x;
    int bh = blockIdx.x >> 2, mq = blockIdx.x & 3;
    size_t base0 = (size_t)bh * KV_P * PSZ;
    float Lp[KV_P];
    float gm = -1e30f;
#pragma unroll
    for (int p = 0; p < KV_P; p++) {
        Lp[p] = kvp[base0 + p * PSZ + 8480];
        gm = fmaxf(gm, Lp[p]);
    }
    if (t < 32) {
        float s = 0.f;
#pragma unroll
        for (int p = 0; p < KV_P; p++) s += kvp[base0 + p * PSZ + 8448 + t];
        vst[t] = s;
    }
    __syncthreads();
    int m = mq * 64 + (t >> 2);
    int d0 = (t & 3) * 8;
    float4 av0 = {0.f, 0.f, 0.f, 0.f}, av1 = {0.f, 0.f, 0.f, 0.f};
    float S = 0.f;
#pragma unroll
    for (int p = 0; p < KV_P; p++) {
        float e = __expf(Lp[p] - gm);
        size_t pb = base0 + p * PSZ;
        float4 a = *reinterpret_cast<const float4*>(&kvp[pb + m * 32 + d0]);
        float4 bq = *reinterpret_cast<const float4*>(&kvp[pb + m * 32 + d0 + 4]);
        av0.x += e * a.x; av0.y += e * a.y; av0.z += e * a.z; av0.w += e * a.w;
        av1.x += e * bq.x; av1.y += e * bq.y; av1.z += e * bq.z; av1.w += e * bq.w;
        if ((t & 3) == 0) S += e * kvp[pb + 8192 + m];
    }
    float o[8];
    o[0] = av0.x; o[1] = av0.y; o[2] = av0.z; o[3] = av0.w;
    o[4] = av1.x; o[5] = av1.y; o[6] = av1.z; o[7] = av1.w;
#pragma unroll
    for (int j = 0; j < 8; j++) {
        float v = (o[j] + 1e-4f * vst[d0 + j]) * 0.0625f;
        kvTb[((size_t)bh * 32 + d0 + j) * 256 + m] = f2bf(v);
    }
    if ((t & 3) == 0) ksumf[bh * 256 + m] = (S + 1e-4f * (float)N) * 0.0625f;
}

// ---------------- q-side fused attention ----------------
#define ATT_TILES 8
__global__ __launch_bounds__(256) void attn_kernel(const unsigned short* __restrict__ qkv16,
                                                   const unsigned short* __restrict__ projbf,
                                                   const unsigned short* __restrict__ kvTb,
                                                   const float* __restrict__ ksumf,
                                                   unsigned short* __restrict__ attn16) {
    __shared__ __align__(16) unsigned short qp_s[64 * 256];   // 32 KB, swizzled
    int t = threadIdx.x;
    int l = t & 63, w = t >> 6;
    int lr = l & 15, lg = l >> 4;
    int bh = blockIdx.x, b = bh >> 3, h = bh & 7;
    int swz = (lr & 7) << 3;
    int row = w * 16 + lr;

    const unsigned short* kvb = kvTb + (size_t)bh * 32 * 256;
    short8 kva0[8], kva1[8];
#pragma unroll
    for (int k0 = 0; k0 < 8; k0++) {
        kva0[k0] = *reinterpret_cast<const short8*>(kvb + (size_t)lr * 256 + k0 * 32 + lg * 8);
        kva1[k0] = *reinterpret_cast<const short8*>(kvb + (size_t)(16 + lr) * 256 + k0 * 32 + lg * 8);
    }

    int tile0 = blockIdx.y * ATT_TILES;
    size_t qstep = (size_t)64 * 768;
    size_t qbase = ((size_t)(b * N) + tile0 * 64 + w * 16 + lr) * 768 + h * 32 + lg * 8;
    short8 qf = *reinterpret_cast<const short8*>(qkv16 + qbase);

    for (int tl = 0; tl < ATT_TILES; tl++) {
        short8 qfn = qf;
        if (tl < ATT_TILES - 1)
            qfn = *reinterpret_cast<const short8*>(qkv16 + qbase + (size_t)(tl + 1) * qstep);

        float sq = 0.f;
#pragma unroll
        for (int e = 0; e < 8; e++) {
            float xx = bfu2f((unsigned short)qf[e]);
            sq += xx * xx;
        }
        sq += __shfl_xor(sq, 16);
        sq += __shfl_xor(sq, 32);
        float dg = 0.5f * sq;

        f32x4 ua[16];
#pragma unroll
        for (int f = 0; f < 16; f++) {
            short8 bq = *reinterpret_cast<const short8*>(projbf + (f * 16 + lr) * 32 + lg * 8);
            ua[f] = __builtin_amdgcn_mfma_f32_16x16x32_bf16(bq, qf, (f32x4){0.f, 0.f, 0.f, 0.f}, 0, 0, 0);
        }

        float mx = -1e30f;
#pragma unroll
        for (int f = 0; f < 16; f++)
#pragma unroll
            for (int r = 0; r < 4; r++) mx = fmaxf(mx, ua[f][r]);
        mx = fmaxf(mx, __shfl_xor(mx, 16));
        mx = fmaxf(mx, __shfl_xor(mx, 32));

        float zs = 0.f;
#pragma unroll
        for (int f = 0; f < 16; f++) {
            float4 ks4 = *reinterpret_cast<const float4*>(&ksumf[bh * 256 + f * 16 + lg * 4]);
            float p0 = (__expf(ua[f][0] - dg - mx) + 1e-4f) * 0.0625f;
            float p1 = (__expf(ua[f][1] - dg - mx) + 1e-4f) * 0.0625f;
            float p2 = (__expf(ua[f][2] - dg - mx) + 1e-4f) * 0.0625f;
            float p3 = (__expf(ua[f][3] - dg - mx) + 1e-4f) * 0.0625f;
            zs += p0 * ks4.x + p1 * ks4.y + p2 * ks4.z + p3 * ks4.w;
            short4 o;
            o.x = (short)f2bf(p0); o.y = (short)f2bf(p1);
            o.z = (short)f2bf(p2); o.w = (short)f2bf(p3);
            *reinterpret_cast<short4*>(&qp_s[row * 256 + ((f * 16 + lg * 4) ^ swz)]) = o;
        }
        zs += __shfl_xor(zs, 16);
        zs += __shfl_xor(zs, 32);
        float zf = 1.0f / (zs + 1e-6f);

        f32x4 oacc[2];
        oacc[0] = (f32x4){0.f, 0.f, 0.f, 0.f};
        oacc[1] = (f32x4){0.f, 0.f, 0.f, 0.f};
#pragma unroll
        for (int k0 = 0; k0 < 8; k0++) {
            short8 qpf = *reinterpret_cast<const short8*>(
                &qp_s[row * 256 + ((k0 * 32 + lg * 8) ^ swz)]);
            oacc[0] = __builtin_amdgcn_mfma_f32_16x16x32_bf16(kva0[k0], qpf, oacc[0], 0, 0, 0);
            oacc[1] = __builtin_amdgcn_mfma_f32_16x16x32_bf16(kva1[k0], qpf, oacc[1], 0, 0, 0);
        }
        size_t orow = ((size_t)(b * N) + (tile0 + tl) * 64 + w * 16 + lr) * 256 + h * 32;
#pragma unroll
        for (int dd = 0; dd < 2; dd++) {
            short4 o;
            o.x = (short)f2bf(oacc[dd][0] * zf);
            o.y = (short)f2bf(oacc[dd][1] * zf);
            o.z = (short)f2bf(oacc[dd][2] * zf);
            o.w = (short)f2bf(oacc[dd][3] * zf);
            *reinterpret_cast<short4*>(&attn16[orow + dd * 16 + lg * 4]) = o;
        }
        qf = qfn;
    }
}

extern "C" void kernel_launch(void* const* d_in, const int* in_sizes, int n_in,
                              void* d_out, int out_size, void* d_ws, size_t ws_size,
                              hipStream_t stream) {
    const float* x = (const float*)d_in[0];
    const float* pos = (const float*)d_in[1];
    const float* g1 = (const float*)d_in[2];
    const float* b1 = (const float*)d_in[3];
    const float* g2 = (const float*)d_in[4];
    const float* b2 = (const float*)d_in[5];
    const float* Wqkv = (const float*)d_in[6];
    const float* Wproj = (const float*)d_in[7];
    const float* bproj = (const float*)d_in[8];
    const float* W1 = (const float*)d_in[9];
    const float* b1m = (const float*)d_in[10];
    const float* W2 = (const float*)d_in[11];
    const float* b2m = (const float*)d_in[12];
    const float* projm = (const float*)d_in[13];

    float* h = (float*)d_out;
    char* p = (char*)d_ws;
    auto alloc = [&](size_t bytes) { char* r = p; p += (bytes + 255) & ~(size_t)255; return r; };
    unsigned short* wbf    = (unsigned short*)alloc((size_t)DEPTH * 786432 * 2);
    unsigned short* projb  = (unsigned short*)alloc((size_t)DEPTH * M * DH * 2);
    unsigned short* ln16   = (unsigned short*)alloc((size_t)B * N * D * 2);
    unsigned short* qkv16  = (unsigned short*)alloc((size_t)B * N * HID * 2);  // union w/ hid16
    unsigned short* hid16  = qkv16;   // qkv dead by MLP1
    unsigned short* attn16 = (unsigned short*)alloc((size_t)B * N * D * 2);
    float* kvp             = (float*)alloc((size_t)64 * KV_P * PSZ * 4);
    unsigned short* kvTb   = (unsigned short*)alloc((size_t)64 * 32 * 256 * 2);
    float* ksumf           = (float*)alloc((size_t)64 * 256 * 4);

    for (int l = 0; l < DEPTH; l++) {
        size_t lb = (size_t)l * 786432;
        wtrans_kernel<<<dim3(768 / 32, 256 / 32), 256, 0, stream>>>(
            Wqkv + (size_t)l * D * 3 * D, wbf + lb + 0, 256, 768, 512);
        wtrans_kernel<<<dim3(256 / 32, 256 / 32), 256, 0, stream>>>(
            Wproj + (size_t)l * D * D, wbf + lb + 196608, 256, 256, 0);
        wtrans_kernel<<<dim3(1024 / 32, 256 / 32), 256, 0, stream>>>(
            W1 + (size_t)l * D * HID, wbf + lb + 262144, 256, 1024, 0);
        wtrans_kernel<<<dim3(256 / 32, 1024 / 32), 256, 0, stream>>>(
            W2 + (size_t)l * HID * D, wbf + lb + 524288, 1024, 256, 0);
    }
    projbf_kernel<<<DEPTH * M * DH / 256, 256, 0, stream>>>(projm, projb);

    add_pos_kernel<<<B * N * D / 256, 256, 0, stream>>>(x, pos, h);

    for (int l = 0; l < DEPTH; l++) {
        size_t lb = (size_t)l * 786432;
        const unsigned short* wqT = wbf + lb + 0;
        const unsigned short* wpT = wbf + lb + 196608;
        const unsigned short* w1T = wbf + lb + 262144;
        const unsigned short* w2T = wbf + lb + 524288;
        const float* bp = bproj + (size_t)l * D;
        const float* b1l = b1m + (size_t)l * HID;
        const float* b2l = b2m + (size_t)l * D;
        const unsigned short* prb = projb + (size_t)l * M * DH;

        ln_kernel<<<B * N / 4, 256, 0, stream>>>(h, g1, b1, ln16);
        mgemm_kernel<false, false, false, true><<<dim3(768 / 128, B * N / 128), 256, 0, stream>>>(
            ln16, wqT, nullptr, nullptr, qkv16, 256, 768);
        kv_kernel<<<dim3(B * H, KV_P), 256, 0, stream>>>(qkv16, prb, kvp);
        kv_combine_kernel<<<B * H * 4, 256, 0, stream>>>(kvp, kvTb, ksumf);
        attn_kernel<<<dim3(B * H, (N / 64) / ATT_TILES), 256, 0, stream>>>(
            qkv16, prb, kvTb, ksumf, attn16);
        mgemm_kernel<true, false, true, false><<<dim3(256 / 128, B * N / 128), 256, 0, stream>>>(
            attn16, wpT, bp, h, nullptr, 256, 256);
        ln_kernel<<<B * N / 4, 256, 0, stream>>>(h, g2, b2, ln16);
        mgemm_kernel<true, true, false, true><<<dim3(1024 / 128, B * N / 128), 256, 0, stream>>>(
            ln16, w1T, b1l, nullptr, hid16, 256, 1024);
        mgemm_kernel<true, false, true, false><<<dim3(256 / 128, B * N / 128), 256, 0, stream>>>(
            hid16, w2T, b2l, h, nullptr, 1024, 256);
    }
}

// Round 12
// 913.336 us; speedup vs baseline: 2.0431x; 1.0676x over previous
//
#include <hip/hip_runtime.h>
#include <hip/hip_bf16.h>
#include <math.h>

#define B 8
#define N 4096
#define D 256
#define H 8
#define DH 32
#define M 256
#define DEPTH 4
#define HID 1024
#define NRM 0.4204482076268573f   // 32^-0.25

typedef __attribute__((ext_vector_type(8))) short short8;
typedef __attribute__((ext_vector_type(4))) float f32x4;

static __device__ __forceinline__ unsigned short f2bf(float f) {
    __hip_bfloat16 h = __float2bfloat16(f);
    return __builtin_bit_cast(unsigned short, h);
}
static __device__ __forceinline__ float bfu2f(unsigned short u) {
    unsigned int x = ((unsigned int)u) << 16;
    return __builtin_bit_cast(float, x);
}

// ---------------- h = x + pos ----------------
__global__ void add_pos_kernel(const float* __restrict__ x, const float* __restrict__ pos,
                               float* __restrict__ h) {
    int i = blockIdx.x * 256 + threadIdx.x;
    int nd = i % (N * D);
    h[i] = x[i] + pos[nd];
}

// ---------------- proj fp32 -> bf16 copy ----------------
__global__ void projbf_kernel(const float* __restrict__ in, unsigned short* __restrict__ out) {
    int i = blockIdx.x * 256 + threadIdx.x;     // DEPTH*M*DH elements
    out[i] = f2bf(in[i]);
}

// ---- weight fp32 (K x N) -> bf16 transposed (N x K), cols < slim scaled by NRM ----
__global__ __launch_bounds__(256) void wtrans_kernel(const float* __restrict__ in,
                                                     unsigned short* __restrict__ out,
                                                     int Kd, int Nd, int slim) {
    __shared__ float tl[32][33];
    int n0 = blockIdx.x * 32, k0 = blockIdx.y * 32;
    int t = threadIdx.x;
    int kk = t >> 3, c4 = (t & 7) * 4;
    float4 v = *reinterpret_cast<const float4*>(&in[(size_t)(k0 + kk) * Nd + n0 + c4]);
    tl[kk][c4 + 0] = v.x; tl[kk][c4 + 1] = v.y; tl[kk][c4 + 2] = v.z; tl[kk][c4 + 3] = v.w;
    __syncthreads();
    int nn = t >> 3, k4 = (t & 7) * 4;
    float sc = (n0 + nn < slim) ? NRM : 1.0f;
    ushort4 o;
    o.x = f2bf(tl[k4 + 0][nn] * sc); o.y = f2bf(tl[k4 + 1][nn] * sc);
    o.z = f2bf(tl[k4 + 2][nn] * sc); o.w = f2bf(tl[k4 + 3][nn] * sc);
    *reinterpret_cast<ushort4*>(&out[(size_t)(n0 + nn) * Kd + k0 + k4]) = o;
}

// ---------------- LayerNorm -> bf16 ----------------
__global__ __launch_bounds__(256) void ln_kernel(const float* __restrict__ in,
                                                 const float* __restrict__ g,
                                                 const float* __restrict__ bb,
                                                 unsigned short* __restrict__ out) {
    int wave = threadIdx.x >> 6, lane = threadIdx.x & 63;
    long row = (long)blockIdx.x * 4 + wave;
    float4 v = reinterpret_cast<const float4*>(in + row * D)[lane];
    float s = v.x + v.y + v.z + v.w;
#pragma unroll
    for (int o = 32; o >= 1; o >>= 1) s += __shfl_xor(s, o);
    float mu = s * (1.0f / D);
    float d0 = v.x - mu, d1 = v.y - mu, d2 = v.z - mu, d3 = v.w - mu;
    float ss = d0 * d0 + d1 * d1 + d2 * d2 + d3 * d3;
#pragma unroll
    for (int o = 32; o >= 1; o >>= 1) ss += __shfl_xor(ss, o);
    float inv = rsqrtf(ss * (1.0f / D) + 1e-6f);
    float4 gv = reinterpret_cast<const float4*>(g)[lane];
    float4 bv = reinterpret_cast<const float4*>(bb)[lane];
    ushort4 o4;
    o4.x = f2bf(d0 * inv * gv.x + bv.x);
    o4.y = f2bf(d1 * inv * gv.y + bv.y);
    o4.z = f2bf(d2 * inv * gv.z + bv.z);
    o4.w = f2bf(d3 * inv * gv.w + bv.w);
    *reinterpret_cast<ushort4*>(&out[row * D + lane * 4]) = o4;
}

// ---------------- bf16 MFMA GEMM: out = A(MxK) @ Bt(NxK)^T ----------------
template <bool BIAS, bool GELU_ACT, bool RESID, bool OUT16>
__global__ __launch_bounds__(256) void mgemm_kernel(const unsigned short* __restrict__ A,
                                                    const unsigned short* __restrict__ Bt,
                                                    const float* __restrict__ bias,
                                                    float* __restrict__ C,
                                                    unsigned short* __restrict__ O16,
                                                    int K, int Nc) {
    __shared__ short Als[128][40];
    __shared__ short Bls[128][40];
    int t = threadIdx.x;
    int l = t & 63, w = t >> 6;
    int wr = w >> 1, wc = w & 1;
    int nwg = gridDim.x * gridDim.y;
    int bid = blockIdx.y * gridDim.x + blockIdx.x;
    int lgid = (bid & 7) * (nwg >> 3) + (bid >> 3);
    int bx = lgid % gridDim.x;
    int by = lgid / gridDim.x;
    long m0 = (long)by * 128;
    int n0 = bx * 128;
    int lr = l & 15;
    int lg = l >> 4;
    int kp8 = lg * 8;
    int srow = t >> 2, skoff = (t & 3) * 8;

    const unsigned short* Ap0 = &A[(size_t)(m0 + srow) * K + skoff];
    const unsigned short* Ap1 = Ap0 + (size_t)64 * K;
    const unsigned short* Bp0 = &Bt[(size_t)(n0 + srow) * K + skoff];
    const unsigned short* Bp1 = Bp0 + (size_t)64 * K;

    short8 ra0 = *reinterpret_cast<const short8*>(Ap0);
    short8 ra1 = *reinterpret_cast<const short8*>(Ap1);
    short8 rb0 = *reinterpret_cast<const short8*>(Bp0);
    short8 rb1 = *reinterpret_cast<const short8*>(Bp1);

    f32x4 acc[4][4];
#pragma unroll
    for (int i = 0; i < 4; i++)
#pragma unroll
        for (int j = 0; j < 4; j++) acc[i][j] = (f32x4){0.f, 0.f, 0.f, 0.f};

    for (int k0 = 0; k0 < K; k0 += 32) {
        *reinterpret_cast<short8*>(&Als[srow][skoff]) = ra0;
        *reinterpret_cast<short8*>(&Als[srow + 64][skoff]) = ra1;
        *reinterpret_cast<short8*>(&Bls[srow][skoff]) = rb0;
        *reinterpret_cast<short8*>(&Bls[srow + 64][skoff]) = rb1;
        __syncthreads();
        if (k0 + 32 < K) {
            ra0 = *reinterpret_cast<const short8*>(Ap0 + k0 + 32);
            ra1 = *reinterpret_cast<const short8*>(Ap1 + k0 + 32);
            rb0 = *reinterpret_cast<const short8*>(Bp0 + k0 + 32);
            rb1 = *reinterpret_cast<const short8*>(Bp1 + k0 + 32);
        }
        short8 a[4], b[4];
#pragma unroll
        for (int i = 0; i < 4; i++)
            a[i] = *reinterpret_cast<const short8*>(&Als[wr * 64 + i * 16 + lr][kp8]);
#pragma unroll
        for (int j = 0; j < 4; j++)
            b[j] = *reinterpret_cast<const short8*>(&Bls[wc * 64 + j * 16 + lr][kp8]);
#pragma unroll
        for (int i = 0; i < 4; i++)
#pragma unroll
            for (int j = 0; j < 4; j++)
                acc[i][j] = __builtin_amdgcn_mfma_f32_16x16x32_bf16(b[j], a[i], acc[i][j], 0, 0, 0);
        __syncthreads();
    }

    float4 bias4[4];
    if (BIAS) {
#pragma unroll
        for (int j = 0; j < 4; j++)
            bias4[j] = *reinterpret_cast<const float4*>(&bias[n0 + wc * 64 + j * 16 + lg * 4]);
    }
#pragma unroll
    for (int i = 0; i < 4; i++) {
        long grow = m0 + wr * 64 + i * 16 + lr;
#pragma unroll
        for (int j = 0; j < 4; j++) {
            int gcol = n0 + wc * 64 + j * 16 + lg * 4;
            f32x4 v = acc[i][j];
            if (BIAS) {
                v[0] += bias4[j].x; v[1] += bias4[j].y; v[2] += bias4[j].z; v[3] += bias4[j].w;
            }
            if (GELU_ACT) {
#pragma unroll
                for (int r = 0; r < 4; r++)
                    v[r] = 0.5f * v[r] * (1.0f + erff(v[r] * 0.70710678118654752f));
            }
            if (OUT16) {
                short4 o;
                o.x = (short)f2bf(v[0]); o.y = (short)f2bf(v[1]);
                o.z = (short)f2bf(v[2]); o.w = (short)f2bf(v[3]);
                *reinterpret_cast<short4*>(&O16[grow * Nc + gcol]) = o;
            } else if (RESID) {
                float4 c0 = *reinterpret_cast<const float4*>(&C[grow * Nc + gcol]);
                c0.x += v[0]; c0.y += v[1]; c0.z += v[2]; c0.w += v[3];
                *reinterpret_cast<float4*>(&C[grow * Nc + gcol]) = c0;
            } else {
                float4 c0 = {v[0], v[1], v[2], v[3]};
                *reinterpret_cast<float4*>(&C[grow * Nc + gcol]) = c0;
            }
        }
    }
}

// ---------------- kv: unshifted exp accumulation, partials [d][m] ----------------
// exp(u-dg) accumulated raw (u std ~0.8, no overflow); global max applied in combine.
#define KV_P 16
#define KV_ROWS (N / KV_P)      // 256
#define PSZ 8484                // 8192 acc[d][m] + 256 asum + 32 vsum + 1 Lm + pad
__global__ __launch_bounds__(256) void kv_kernel(const unsigned short* __restrict__ qkv16,
                                                 const unsigned short* __restrict__ projbf,
                                                 float* __restrict__ kvp) {
    __shared__ __align__(16) unsigned short kp_s[256][64];    // 32 KB, XOR-swz
    __shared__ __align__(16) unsigned short vT_s[32][66];
    __shared__ float red[4];
    __shared__ float asumred[4][256];
    __shared__ float vred[256][4];
    int t = threadIdx.x;
    int l = t & 63, w = t >> 6;
    int lr = l & 15, lg = l >> 4;
    int bh = blockIdx.x, b = bh >> 3, h = bh & 7;
    int n0 = blockIdx.y * KV_ROWS;
    int rsw = (lr & 7) << 3;

    f32x4 kvacc[4][2];
#pragma unroll
    for (int mf = 0; mf < 4; mf++)
#pragma unroll
        for (int dd = 0; dd < 2; dd++) kvacc[mf][dd] = (f32x4){0.f, 0.f, 0.f, 0.f};
    float asum_p[16];
#pragma unroll
    for (int f = 0; f < 16; f++) asum_p[f] = 0.f;
    float4 vs4 = {0.f, 0.f, 0.f, 0.f};
    float cmax = -1e30f;

    for (int c = 0; c < KV_ROWS / 64; c++) {
        __syncthreads();   // previous chunk's LDS reads complete before overwrite
        size_t kbase = ((size_t)(b * N) + n0 + c * 64 + w * 16 + lr) * 768 + 256 + h * 32 + lg * 8;
        short8 aq = *reinterpret_cast<const short8*>(qkv16 + kbase);
        float sq = 0.f;
#pragma unroll
        for (int e = 0; e < 8; e++) {
            float xx = bfu2f((unsigned short)aq[e]);
            sq += xx * xx;
        }
        sq += __shfl_xor(sq, 16);
        sq += __shfl_xor(sq, 32);
        float dgr[4];
#pragma unroll
        for (int r = 0; r < 4; r++) dgr[r] = 0.5f * __shfl(sq, lg * 4 + r);
        int cbase = (w * 16 + lg * 4) ^ rsw;
        // ---- fused: u-MFMA -> exp -> kp_s (one fragment live at a time) ----
#pragma unroll
        for (int f = 0; f < 16; f++) {
            short8 bq = *reinterpret_cast<const short8*>(projbf + (f * 16 + lr) * 32 + lg * 8);
            f32x4 u = __builtin_amdgcn_mfma_f32_16x16x32_bf16(aq, bq, (f32x4){0.f, 0.f, 0.f, 0.f}, 0, 0, 0);
            cmax = fmaxf(cmax, fmaxf(fmaxf(u[0], u[1]), fmaxf(u[2], u[3])));
            float p0 = __expf(u[0] - dgr[0]);
            float p1 = __expf(u[1] - dgr[1]);
            float p2 = __expf(u[2] - dgr[2]);
            float p3 = __expf(u[3] - dgr[3]);
            asum_p[f] += p0 + p1 + p2 + p3;
            short4 o;
            o.x = (short)f2bf(p0); o.y = (short)f2bf(p1);
            o.z = (short)f2bf(p2); o.w = (short)f2bf(p3);
            *reinterpret_cast<short4*>(&kp_s[f * 16 + lr][cbase]) = o;
        }
        // ---- stage v^T (bf16) ----
#pragma unroll
        for (int ii = 0; ii < 2; ii++) {
            int idx = t + ii * 256;
            int nn = idx >> 3, dz = (idx & 7) * 4;
            const unsigned short* vp =
                qkv16 + ((size_t)(b * N) + n0 + c * 64 + nn) * 768 + 512 + h * 32 + dz;
            short4 vv = *reinterpret_cast<const short4*>(vp);
            float v0 = bfu2f((unsigned short)vv.x), v1 = bfu2f((unsigned short)vv.y);
            float v2 = bfu2f((unsigned short)vv.z), v3 = bfu2f((unsigned short)vv.w);
            vs4.x += v0; vs4.y += v1; vs4.z += v2; vs4.w += v3;
            vT_s[dz + 0][nn] = (unsigned short)vv.x; vT_s[dz + 1][nn] = (unsigned short)vv.y;
            vT_s[dz + 2][nn] = (unsigned short)vv.z; vT_s[dz + 3][nn] = (unsigned short)vv.w;
        }
        __syncthreads();
        // ---- kv += kp^T @ v ----
#pragma unroll
        for (int ks = 0; ks < 2; ks++) {
            short8 bv0 = *reinterpret_cast<const short8*>(&vT_s[lr][ks * 32 + lg * 8]);
            short8 bv1 = *reinterpret_cast<const short8*>(&vT_s[16 + lr][ks * 32 + lg * 8]);
#pragma unroll
            for (int mf = 0; mf < 4; mf++) {
                short8 am = *reinterpret_cast<const short8*>(
                    &kp_s[w * 64 + mf * 16 + lr][(ks * 32 + lg * 8) ^ rsw]);
                kvacc[mf][0] = __builtin_amdgcn_mfma_f32_16x16x32_bf16(am, bv0, kvacc[mf][0], 0, 0, 0);
                kvacc[mf][1] = __builtin_amdgcn_mfma_f32_16x16x32_bf16(am, bv1, kvacc[mf][1], 0, 0, 0);
            }
        }
    }
    // ---- reductions ----
#pragma unroll
    for (int f = 0; f < 16; f++) {
        asum_p[f] += __shfl_xor(asum_p[f], 16);
        asum_p[f] += __shfl_xor(asum_p[f], 32);
    }
    if (l < 16) {
#pragma unroll
        for (int f = 0; f < 16; f++) asumred[w][f * 16 + l] = asum_p[f];
    }
    vred[t][0] = vs4.x; vred[t][1] = vs4.y; vred[t][2] = vs4.z; vred[t][3] = vs4.w;
#pragma unroll
    for (int o = 1; o < 64; o <<= 1) cmax = fmaxf(cmax, __shfl_xor(cmax, o));
    if (l == 0) red[w] = cmax;
    __syncthreads();
    size_t base = ((size_t)bh * KV_P + blockIdx.y) * PSZ;
    // ---- acc partial store, layout [d][m] -> float4 ----
#pragma unroll
    for (int mf = 0; mf < 4; mf++)
#pragma unroll
        for (int dd = 0; dd < 2; dd++) {
            int m = w * 64 + mf * 16 + lg * 4;
            int d = dd * 16 + lr;
            float4 o;
            o.x = kvacc[mf][dd][0]; o.y = kvacc[mf][dd][1];
            o.z = kvacc[mf][dd][2]; o.w = kvacc[mf][dd][3];
            *reinterpret_cast<float4*>(&kvp[base + (size_t)d * 256 + m]) = o;
        }
    {
        float s = asumred[0][t] + asumred[1][t] + asumred[2][t] + asumred[3][t];
        kvp[base + 8192 + t] = s;
    }
    if (t < 32) {
        int f4g = t >> 2, cc = t & 3;
        float s = 0.f;
#pragma unroll
        for (int g = 0; g < 32; g++) s += vred[g * 8 + f4g][cc];
        kvp[base + 8448 + t] = s;
    }
    if (t == 0) kvp[base + 8480] = fmaxf(fmaxf(red[0], red[1]), fmaxf(red[2], red[3]));
}

// ---------------- combine partials -> kvT bf16, ksum (grid B*H*4) ----------------
__global__ __launch_bounds__(256) void kv_combine_kernel(const float* __restrict__ kvp,
                                                         unsigned short* __restrict__ kvTb,
                                                         float* __restrict__ ksumf) {
    __shared__ float vst[32];
    int t = threadIdx.x;
    int bh = blockIdx.x >> 2, dq = blockIdx.x & 3;
    size_t base0 = (size_t)bh * KV_P * PSZ;
    float gm = -1e30f;
#pragma unroll
    for (int p = 0; p < KV_P; p++) gm = fmaxf(gm, kvp[base0 + p * PSZ + 8480]);
    if (t < 32) {
        float s = 0.f;
#pragma unroll
        for (int p = 0; p < KV_P; p++) s += kvp[base0 + p * PSZ + 8448 + t];
        vst[t] = s;
    }
    __syncthreads();
    float es = __expf(-gm);
    int d = dq * 8 + (t >> 5);
    int m0 = (t & 31) * 8;
    float4 a0 = {0.f, 0.f, 0.f, 0.f}, a1 = {0.f, 0.f, 0.f, 0.f};
#pragma unroll
    for (int p = 0; p < KV_P; p++) {
        const float* src = &kvp[base0 + p * PSZ + (size_t)d * 256 + m0];
        float4 x0 = *reinterpret_cast<const float4*>(src);
        float4 x1 = *reinterpret_cast<const float4*>(src + 4);
        a0.x += x0.x; a0.y += x0.y; a0.z += x0.z; a0.w += x0.w;
        a1.x += x1.x; a1.y += x1.y; a1.z += x1.z; a1.w += x1.w;
    }
    float vadd = 1e-4f * vst[d];
    ushort4 o0, o1;
    o0.x = f2bf((a0.x * es + vadd) * 0.0625f); o0.y = f2bf((a0.y * es + vadd) * 0.0625f);
    o0.z = f2bf((a0.z * es + vadd) * 0.0625f); o0.w = f2bf((a0.w * es + vadd) * 0.0625f);
    o1.x = f2bf((a1.x * es + vadd) * 0.0625f); o1.y = f2bf((a1.y * es + vadd) * 0.0625f);
    o1.z = f2bf((a1.z * es + vadd) * 0.0625f); o1.w = f2bf((a1.w * es + vadd) * 0.0625f);
    *reinterpret_cast<ushort4*>(&kvTb[((size_t)bh * 32 + d) * 256 + m0]) = o0;
    *reinterpret_cast<ushort4*>(&kvTb[((size_t)bh * 32 + d) * 256 + m0 + 4]) = o1;
    if (dq == 0) {
        float S = 0.f;
#pragma unroll
        for (int p = 0; p < KV_P; p++) S += kvp[base0 + p * PSZ + 8192 + t];
        ksumf[bh * 256 + t] = (S * es + 1e-4f * (float)N) * 0.0625f;
    }
}

// ---------------- q-side fused attention ----------------
#define ATT_TILES 8
__global__ __launch_bounds__(256) void attn_kernel(const unsigned short* __restrict__ qkv16,
                                                   const unsigned short* __restrict__ projbf,
                                                   const unsigned short* __restrict__ kvTb,
                                                   const float* __restrict__ ksumf,
                                                   unsigned short* __restrict__ attn16) {
    __shared__ __align__(16) unsigned short qp_s[64 * 256];   // 32 KB, swizzled
    int t = threadIdx.x;
    int l = t & 63, w = t >> 6;
    int lr = l & 15, lg = l >> 4;
    int bh = blockIdx.x, b = bh >> 3, h = bh & 7;
    int swz = (lr & 7) << 3;
    int row = w * 16 + lr;

    const unsigned short* kvb = kvTb + (size_t)bh * 32 * 256;
    short8 kva0[8], kva1[8];
#pragma unroll
    for (int k0 = 0; k0 < 8; k0++) {
        kva0[k0] = *reinterpret_cast<const short8*>(kvb + (size_t)lr * 256 + k0 * 32 + lg * 8);
        kva1[k0] = *reinterpret_cast<const short8*>(kvb + (size_t)(16 + lr) * 256 + k0 * 32 + lg * 8);
    }

    int tile0 = blockIdx.y * ATT_TILES;
    size_t qstep = (size_t)64 * 768;
    size_t qbase = ((size_t)(b * N) + tile0 * 64 + w * 16 + lr) * 768 + h * 32 + lg * 8;
    short8 qf = *reinterpret_cast<const short8*>(qkv16 + qbase);

    for (int tl = 0; tl < ATT_TILES; tl++) {
        short8 qfn = qf;
        if (tl < ATT_TILES - 1)
            qfn = *reinterpret_cast<const short8*>(qkv16 + qbase + (size_t)(tl + 1) * qstep);

        float sq = 0.f;
#pragma unroll
        for (int e = 0; e < 8; e++) {
            float xx = bfu2f((unsigned short)qf[e]);
            sq += xx * xx;
        }
        sq += __shfl_xor(sq, 16);
        sq += __shfl_xor(sq, 32);
        float dg = 0.5f * sq;

        f32x4 ua[16];
#pragma unroll
        for (int f = 0; f < 16; f++) {
            short8 bq = *reinterpret_cast<const short8*>(projbf + (f * 16 + lr) * 32 + lg * 8);
            ua[f] = __builtin_amdgcn_mfma_f32_16x16x32_bf16(bq, qf, (f32x4){0.f, 0.f, 0.f, 0.f}, 0, 0, 0);
        }

        float mx = -1e30f;
#pragma unroll
        for (int f = 0; f < 16; f++)
#pragma unroll
            for (int r = 0; r < 4; r++) mx = fmaxf(mx, ua[f][r]);
        mx = fmaxf(mx, __shfl_xor(mx, 16));
        mx = fmaxf(mx, __shfl_xor(mx, 32));

        float zs = 0.f;
#pragma unroll
        for (int f = 0; f < 16; f++) {
            float4 ks4 = *reinterpret_cast<const float4*>(&ksumf[bh * 256 + f * 16 + lg * 4]);
            float p0 = (__expf(ua[f][0] - dg - mx) + 1e-4f) * 0.0625f;
            float p1 = (__expf(ua[f][1] - dg - mx) + 1e-4f) * 0.0625f;
            float p2 = (__expf(ua[f][2] - dg - mx) + 1e-4f) * 0.0625f;
            float p3 = (__expf(ua[f][3] - dg - mx) + 1e-4f) * 0.0625f;
            zs += p0 * ks4.x + p1 * ks4.y + p2 * ks4.z + p3 * ks4.w;
            short4 o;
            o.x = (short)f2bf(p0); o.y = (short)f2bf(p1);
            o.z = (short)f2bf(p2); o.w = (short)f2bf(p3);
            *reinterpret_cast<short4*>(&qp_s[row * 256 + ((f * 16 + lg * 4) ^ swz)]) = o;
        }
        zs += __shfl_xor(zs, 16);
        zs += __shfl_xor(zs, 32);
        float zf = 1.0f / (zs + 1e-6f);

        f32x4 oacc[2];
        oacc[0] = (f32x4){0.f, 0.f, 0.f, 0.f};
        oacc[1] = (f32x4){0.f, 0.f, 0.f, 0.f};
#pragma unroll
        for (int k0 = 0; k0 < 8; k0++) {
            short8 qpf = *reinterpret_cast<const short8*>(
                &qp_s[row * 256 + ((k0 * 32 + lg * 8) ^ swz)]);
            oacc[0] = __builtin_amdgcn_mfma_f32_16x16x32_bf16(kva0[k0], qpf, oacc[0], 0, 0, 0);
            oacc[1] = __builtin_amdgcn_mfma_f32_16x16x32_bf16(kva1[k0], qpf, oacc[1], 0, 0, 0);
        }
        size_t orow = ((size_t)(b * N) + (tile0 + tl) * 64 + w * 16 + lr) * 256 + h * 32;
#pragma unroll
        for (int dd = 0; dd < 2; dd++) {
            short4 o;
            o.x = (short)f2bf(oacc[dd][0] * zf);
            o.y = (short)f2bf(oacc[dd][1] * zf);
            o.z = (short)f2bf(oacc[dd][2] * zf);
            o.w = (short)f2bf(oacc[dd][3] * zf);
            *reinterpret_cast<short4*>(&attn16[orow + dd * 16 + lg * 4]) = o;
        }
        qf = qfn;
    }
}

extern "C" void kernel_launch(void* const* d_in, const int* in_sizes, int n_in,
                              void* d_out, int out_size, void* d_ws, size_t ws_size,
                              hipStream_t stream) {
    const float* x = (const float*)d_in[0];
    const float* pos = (const float*)d_in[1];
    const float* g1 = (const float*)d_in[2];
    const float* b1 = (const float*)d_in[3];
    const float* g2 = (const float*)d_in[4];
    const float* b2 = (const float*)d_in[5];
    const float* Wqkv = (const float*)d_in[6];
    const float* Wproj = (const float*)d_in[7];
    const float* bproj = (const float*)d_in[8];
    const float* W1 = (const float*)d_in[9];
    const float* b1m = (const float*)d_in[10];
    const float* W2 = (const float*)d_in[11];
    const float* b2m = (const float*)d_in[12];
    const float* projm = (const float*)d_in[13];

    float* h = (float*)d_out;
    char* p = (char*)d_ws;
    auto alloc = [&](size_t bytes) { char* r = p; p += (bytes + 255) & ~(size_t)255; return r; };
    unsigned short* wbf    = (unsigned short*)alloc((size_t)DEPTH * 786432 * 2);
    unsigned short* projb  = (unsigned short*)alloc((size_t)DEPTH * M * DH * 2);
    unsigned short* ln16   = (unsigned short*)alloc((size_t)B * N * D * 2);
    unsigned short* qkv16  = (unsigned short*)alloc((size_t)B * N * HID * 2);  // union w/ hid16
    unsigned short* hid16  = qkv16;   // qkv dead by MLP1
    unsigned short* attn16 = (unsigned short*)alloc((size_t)B * N * D * 2);
    float* kvp             = (float*)alloc((size_t)64 * KV_P * PSZ * 4);
    unsigned short* kvTb   = (unsigned short*)alloc((size_t)64 * 32 * 256 * 2);
    float* ksumf           = (float*)alloc((size_t)64 * 256 * 4);

    for (int l = 0; l < DEPTH; l++) {
        size_t lb = (size_t)l * 786432;
        wtrans_kernel<<<dim3(768 / 32, 256 / 32), 256, 0, stream>>>(
            Wqkv + (size_t)l * D * 3 * D, wbf + lb + 0, 256, 768, 512);
        wtrans_kernel<<<dim3(256 / 32, 256 / 32), 256, 0, stream>>>(
            Wproj + (size_t)l * D * D, wbf + lb + 196608, 256, 256, 0);
        wtrans_kernel<<<dim3(1024 / 32, 256 / 32), 256, 0, stream>>>(
            W1 + (size_t)l * D * HID, wbf + lb + 262144, 256, 1024, 0);
        wtrans_kernel<<<dim3(256 / 32, 1024 / 32), 256, 0, stream>>>(
            W2 + (size_t)l * HID * D, wbf + lb + 524288, 1024, 256, 0);
    }
    projbf_kernel<<<DEPTH * M * DH / 256, 256, 0, stream>>>(projm, projb);

    add_pos_kernel<<<B * N * D / 256, 256, 0, stream>>>(x, pos, h);

    for (int l = 0; l < DEPTH; l++) {
        size_t lb = (size_t)l * 786432;
        const unsigned short* wqT = wbf + lb + 0;
        const unsigned short* wpT = wbf + lb + 196608;
        const unsigned short* w1T = wbf + lb + 262144;
        const unsigned short* w2T = wbf + lb + 524288;
        const float* bp = bproj + (size_t)l * D;
        const float* b1l = b1m + (size_t)l * HID;
        const float* b2l = b2m + (size_t)l * D;
        const unsigned short* prb = projb + (size_t)l * M * DH;

        ln_kernel<<<B * N / 4, 256, 0, stream>>>(h, g1, b1, ln16);
        mgemm_kernel<false, false, false, true><<<dim3(768 / 128, B * N / 128), 256, 0, stream>>>(
            ln16, wqT, nullptr, nullptr, qkv16, 256, 768);
        kv_kernel<<<dim3(B * H, KV_P), 256, 0, stream>>>(qkv16, prb, kvp);
        kv_combine_kernel<<<B * H * 4, 256, 0, stream>>>(kvp, kvTb, ksumf);
        attn_kernel<<<dim3(B * H, (N / 64) / ATT_TILES), 256, 0, stream>>>(
            qkv16, prb, kvTb, ksumf, attn16);
        mgemm_kernel<true, false, true, false><<<dim3(256 / 128, B * N / 128), 256, 0, stream>>>(
            attn16, wpT, bp, h, nullptr, 256, 256);
        ln_kernel<<<B * N / 4, 256, 0, stream>>>(h, g2, b2, ln16);
        mgemm_kernel<true, true, false, true><<<dim3(1024 / 128, B * N / 128), 256, 0, stream>>>(
            ln16, w1T, b1l, nullptr, hid16, 256, 1024);
        mgemm_kernel<true, false, true, false><<<dim3(256 / 128, B * N / 128), 256, 0, stream>>>(
            hid16, w2T, b2l, h, nullptr, 1024, 256);
    }
}